// Round 10
// baseline (231.534 us; speedup 1.0000x reference)
//
#include <hip/hip_runtime.h>
#include <hip/hip_cooperative_groups.h>
#include <math.h>

namespace cg = cooperative_groups;

#define DD 256
#define NN 4096
#define EPSV 1e-6f

typedef unsigned long long u64;
typedef __attribute__((ext_vector_type(8))) short short8v;
typedef __attribute__((ext_vector_type(8))) unsigned short ushort8v;
typedef __attribute__((ext_vector_type(4))) float f32x4;

// async 16B global->LDS copy (per-lane global addr, wave-uniform LDS base)
__device__ __forceinline__ void gll16(const unsigned short* g, unsigned short* l) {
  __builtin_amdgcn_global_load_lds(
      (const __attribute__((address_space(1))) unsigned int*)(const void*)g,
      (__attribute__((address_space(3))) unsigned int*)(void*)l, 16, 0, 0);
}

// ---------------- fused cooperative kernel ----------------
// 256 blocks x 512 threads (8 waves), 1 block/CU guaranteed co-resident
// (LDS 64KB <= 160KB, launch_bounds(512,2) caps VGPR at 256 -> 2 waves/EU).
// Phase 1: prep 16 rows/block: sq norms, key init, fp32->bf16(hi) in MFMA
//   fragment order: lane l of frag (rowgroup g, kslice s) holds
//   E[16g+(l&15)][32s+(l>>4)*8..+7], flat hi[((g*8+s)*64+l)*8+e].
// Phase 2: one 256x256 gram tile per block (16x16 tiles, XCD-swizzled):
//   A panel (32 rows/wave) in regs; B staged in two 64KB halves via gll16;
//   min/max folded across both halves in registers -> 1 atomic per row/block.
// Phase 3: exact fp32 triplet terms + block partial + one atomicAdd.
__global__ __launch_bounds__(512, 2) void fused_kernel(const float* __restrict__ emb,
                                                       float* __restrict__ sq,
                                                       unsigned short* __restrict__ hi,
                                                       u64* __restrict__ posk,
                                                       u64* __restrict__ negk,
                                                       float* __restrict__ out) {
  __shared__ __attribute__((aligned(16))) unsigned short ldsB[8][4096];  // 64 KB
  cg::grid_group grid = cg::this_grid();

  const int bid = blockIdx.x;   // 0..255
  const int t = threadIdx.x;    // 0..511
  const int lane = t & 63;
  const int w = t >> 6;         // wave 0..7
  const int fr = lane & 15;
  const int grp = lane >> 4;

  // ================= phase 1: prep =================
  {
    const int row = bid * 16 + (t >> 5);
    const int k0 = (t & 31) * 8;
    const float* src = emb + (size_t)row * DD + k0;
    float4 v0 = *reinterpret_cast<const float4*>(src);
    float4 v1 = *reinterpret_cast<const float4*>(src + 4);
    float f[8] = {v0.x, v0.y, v0.z, v0.w, v1.x, v1.y, v1.z, v1.w};
    ushort8v h;
    float s = 0.f;
    #pragma unroll
    for (int e = 0; e < 8; ++e) {
      s += f[e] * f[e];
      h[e] = (unsigned short)(__float_as_uint(f[e]) >> 16);
    }
    const int g = row >> 4;
    const int sl = (t & 31) >> 2;            // kslice = k0>>5
    const int l = (row & 15) + (t & 3) * 16; // frag lane
    *reinterpret_cast<ushort8v*>(hi + ((size_t)(g * 8 + sl) * 64 + l) * 8) = h;
    #pragma unroll
    for (int off = 1; off < 32; off <<= 1) s += __shfl_xor(s, off);
    if ((t & 31) == 0) {
      sq[row] = s;
      posk[row] = 0ull;   // max-key init
      negk[row] = ~0ull;  // min-key init
    }
    if (bid == 0 && t == 0) out[0] = 0.0f;
  }
  __threadfence();
  grid.sync();

  // ================= phase 2: mine one 256x256 tile =================
  {
    // XCD swizzle: 32 blocks/XCD get 2 consecutive ib-stripes x all 16 jb
    const int xcd = bid & 7, idx = bid >> 3;      // idx 0..31
    const int ib = xcd * 2 + (idx >> 4);          // 0..15
    const int jb = idx & 15;                      // 0..15
    const bool diag = (ib == jb);
    const int ibRow = ib * 256, jbCol = jb * 256;

    // A panel into regs: wave w owns rows [ibRow+32w, +32) = rowgroups ib*16+2w+m
    short8v a[8][2];
    #pragma unroll
    for (int m = 0; m < 2; ++m) {
      const unsigned short* ga = hi + ((size_t)(ib * 16 + 2 * w + m) * 8) * 512 + lane * 8;
      #pragma unroll
      for (int s = 0; s < 8; ++s)
        a[s][m] = *reinterpret_cast<const short8v*>(ga + s * 512);
    }

    int gi_[2][4]; float sqiv[2][4];
    #pragma unroll
    for (int m = 0; m < 2; ++m)
      #pragma unroll
      for (int r = 0; r < 4; ++r) {
        gi_[m][r] = ibRow + 32 * w + 16 * m + 4 * grp + r;
        sqiv[m][r] = sq[gi_[m][r]];
      }

    float pv[2][4], nv[2][4]; int pj[2][4], nj[2][4];
    #pragma unroll
    for (int m = 0; m < 2; ++m)
      #pragma unroll
      for (int r = 0; r < 4; ++r) {
        pv[m][r] = -1.0f;   pj[m][r] = -1;
        nv[m][r] = 3.0e38f; nj[m][r] = 0x7fffffff;
      }

    #pragma unroll 1
    for (int h2 = 0; h2 < 2; ++h2) {
      __syncthreads();  // protect LDS from previous half's readers
      // stage B half: wave w stages col-rowgroup jb*16 + h2*8 + w, all 8 slices
      {
        const unsigned short* gB =
            hi + ((size_t)(jb * 16 + h2 * 8 + w) * 8) * 512 + lane * 8;
        #pragma unroll
        for (int s = 0; s < 8; ++s) gll16(gB + s * 512, &ldsB[s][w * 512]);
      }
      __syncthreads();  // vmcnt(0) drain + barrier: half staged

      f32x4 acc[2][8];
      #pragma unroll
      for (int m = 0; m < 2; ++m)
        #pragma unroll
        for (int n = 0; n < 8; ++n) acc[m][n] = (f32x4){0.f, 0.f, 0.f, 0.f};

      #pragma unroll
      for (int s = 0; s < 8; ++s) {
        short8v b[8];
        #pragma unroll
        for (int n = 0; n < 8; ++n)
          b[n] = *reinterpret_cast<const short8v*>(&ldsB[s][n * 512 + lane * 8]);
        #pragma unroll
        for (int m = 0; m < 2; ++m)
          #pragma unroll
          for (int n = 0; n < 8; ++n)
            acc[m][n] = __builtin_amdgcn_mfma_f32_16x16x32_bf16(a[s][m], b[n], acc[m][n], 0, 0, 0);
      }

      // fold this half into running candidates (j strictly increasing ->
      // strict compare keeps first occurrence). C layout: col=lane&15,
      // row=(lane>>4)*4+reg.
      #pragma unroll
      for (int n = 0; n < 8; ++n) {
        const int j = jbCol + h2 * 128 + n * 16 + fr;
        const float sqj = sq[j];
        #pragma unroll
        for (int m = 0; m < 2; ++m)
          #pragma unroll
          for (int r = 0; r < 4; ++r) {
            const float d2 = fmaxf(sqiv[m][r] + sqj - 2.0f * acc[m][n][r], 0.0f);
            const bool isPos = diag && ((j >> 4) == (gi_[m][r] >> 4));
            if (isPos) {
              if (d2 > pv[m][r] || (d2 == pv[m][r] && j < pj[m][r])) { pv[m][r] = d2; pj[m][r] = j; }
            } else {
              if (d2 < nv[m][r] || (d2 == nv[m][r] && j < nj[m][r])) { nv[m][r] = d2; nj[m][r] = j; }
            }
          }
      }
    }

    // 16-lane butterfly reduce + one atomic per row
    #pragma unroll
    for (int m = 0; m < 2; ++m)
      #pragma unroll
      for (int r = 0; r < 4; ++r) {
        float v = nv[m][r]; int vi = nj[m][r];
        #pragma unroll
        for (int off = 1; off < 16; off <<= 1) {
          float ov = __shfl_xor(v, off); int oi = __shfl_xor(vi, off);
          if (ov < v || (ov == v && oi < vi)) { v = ov; vi = oi; }
        }
        float p2 = pv[m][r]; int pq = pj[m][r];
        #pragma unroll
        for (int off = 1; off < 16; off <<= 1) {
          float ov = __shfl_xor(p2, off); int oi = __shfl_xor(pq, off);
          if (ov > p2 || (ov == p2 && ((unsigned)oi < (unsigned)pq))) { p2 = ov; pq = oi; }
        }
        if (fr == 0) {
          atomicMin(&negk[gi_[m][r]], ((u64)__float_as_uint(v) << 32) | (unsigned)vi);
          if (diag && pq >= 0)
            atomicMax(&posk[gi_[m][r]], ((u64)__float_as_uint(p2) << 32) |
                                            (unsigned)(0xFFFFFFFFu - (unsigned)pq));
        }
      }
  }
  __threadfence();
  grid.sync();

  // ================= phase 3: exact fp32 triplet + mean =================
  {
    float* part = (float*)&ldsB[0][0];  // reuse LDS
    const int i = bid * 16 + (t >> 5);
    const int ls = t & 31;

    u64 pk = posk[i], nk = negk[i];
    int p = (int)(0xFFFFFFFFu - (unsigned)(pk & 0xFFFFFFFFu));
    int nidx = (int)(nk & 0xFFFFFFFFu);

    const float* ei = emb + (size_t)i * DD + ls * 8;
    const float* epp = emb + (size_t)p * DD + ls * 8;
    const float* enn = emb + (size_t)nidx * DD + ls * 8;
    float sp = 0.f, sn = 0.f;
    #pragma unroll
    for (int c = 0; c < 2; ++c) {
      float4 e = *reinterpret_cast<const float4*>(ei + 4 * c);
      float4 ep = *reinterpret_cast<const float4*>(epp + 4 * c);
      float4 en = *reinterpret_cast<const float4*>(enn + 4 * c);
      float dp[4] = {e.x - ep.x + EPSV, e.y - ep.y + EPSV, e.z - ep.z + EPSV, e.w - ep.w + EPSV};
      float dn[4] = {e.x - en.x + EPSV, e.y - en.y + EPSV, e.z - en.z + EPSV, e.w - en.w + EPSV};
      #pragma unroll
      for (int q = 0; q < 4; ++q) { sp += dp[q] * dp[q]; sn += dn[q] * dn[q]; }
    }
    #pragma unroll
    for (int off = 1; off < 32; off <<= 1) {
      sp += __shfl_xor(sp, off);
      sn += __shfl_xor(sn, off);
    }
    __syncthreads();
    if (ls == 0) part[t >> 5] = fmaxf(sqrtf(sp) - sqrtf(sn) + 1.0f, 0.0f);
    __syncthreads();
    if (t == 0) {
      float s = 0.f;
      #pragma unroll
      for (int k = 0; k < 16; ++k) s += part[k];
      atomicAdd(out, s * (1.0f / NN));
    }
  }
}

extern "C" void kernel_launch(void* const* d_in, const int* in_sizes, int n_in,
                              void* d_out, int out_size, void* d_ws, size_t ws_size,
                              hipStream_t stream) {
  const float* emb = (const float*)d_in[0];  // [N, D] row-major
  char* ws = (char*)d_ws;
  float* sq = (float*)ws;                  // 16 KB
  u64* posk = (u64*)(ws + (16 << 10));     // 32 KB
  u64* negk = (u64*)(ws + (48 << 10));     // 32 KB
  unsigned short* hi = (unsigned short*)(ws + (96 << 10));  // 2 MB
  float* out = (float*)d_out;

  void* args[] = {(void*)&emb, (void*)&sq, (void*)&hi, (void*)&posk, (void*)&negk, (void*)&out};
  hipLaunchCooperativeKernel((const void*)fused_kernel, dim3(256), dim3(512), args, 0, stream);
}

// Round 11
// 114.032 us; speedup vs baseline: 2.0304x; 2.0304x over previous
//
#include <hip/hip_runtime.h>
#include <math.h>

#define DD 256
#define NN 4096
#define EPSV 1e-6f

typedef unsigned long long u64;
typedef __attribute__((ext_vector_type(8))) short short8v;
typedef __attribute__((ext_vector_type(8))) unsigned short ushort8v;
typedef __attribute__((ext_vector_type(4))) float f32x4;

// ---------------- kernel 0: sq norms + key init (tiny) ----------------
// 256 blocks x 256 threads; 16 lanes per row, 16 rows per block.
__global__ __launch_bounds__(256) void sqinit_kernel(const float* __restrict__ emb,
                                                     float* __restrict__ sq,
                                                     u64* __restrict__ posk,
                                                     u64* __restrict__ negk,
                                                     float* __restrict__ out) {
  const int t = threadIdx.x;
  const int row = blockIdx.x * 16 + (t >> 4);
  const int q = t & 15;
  const float* src = emb + (size_t)row * DD + q * 16;
  float s = 0.f;
  #pragma unroll
  for (int i = 0; i < 4; ++i) {
    float4 v = *reinterpret_cast<const float4*>(src + 4 * i);
    s += v.x * v.x + v.y * v.y + v.z * v.z + v.w * v.w;
  }
  #pragma unroll
  for (int off = 1; off < 16; off <<= 1) s += __shfl_xor(s, off);
  if (q == 0) {
    sq[row] = s;
    posk[row] = 0ull;   // max-key init
    negk[row] = ~0ull;  // min-key init
  }
  if (blockIdx.x == 0 && t == 0) out[0] = 0.0f;
}

// truncate-pack 8 fp32 -> 8 bf16 (hi 16 bits)
__device__ __forceinline__ ushort8v pack8(float4 v0, float4 v1) {
  float f[8] = {v0.x, v0.y, v0.z, v0.w, v1.x, v1.y, v1.z, v1.w};
  ushort8v h;
  #pragma unroll
  for (int e = 0; e < 8; ++e) h[e] = (unsigned short)(__float_as_uint(f[e]) >> 16);
  return h;
}

// ---------------- kernel 1: MFMA gram-tile mining, self-converting --------
// 1024 blocks (XCD-swizzled) = 32x32 tiles of 128x128. 4 waves, wave w owns
// rows [32w,32w+32) x all 128 cols (M_rep=2, N_rep=8). fp32 is loaded from
// emb, truncated to bf16 in-register, B panel ds_write'd to 64KB LDS
// (8 slice-buffers), A panel kept in regs. ONE barrier, then 128 MFMAs/wave
// barrier-free. hi-only bf16 ranking; exact fp32 recompute in triplet_kernel.
// Fragment layout (A=B for Gram): lane l holds row (l&15), k (l>>4)*8+e +32s.
__global__ __launch_bounds__(256, 2) void mine_mfma_kernel(const float* __restrict__ emb,
                                                           const float* __restrict__ sq,
                                                           u64* __restrict__ posk,
                                                           u64* __restrict__ negk) {
  __shared__ __attribute__((aligned(16))) unsigned short ldsB[8][4096];  // 64 KB

  // bijective XCD swizzle: consecutive 128-block chunks per XCD
  const int bid = blockIdx.x;
  const int wg = (bid & 7) * 128 + (bid >> 3);
  const int ib = wg >> 5, jb = wg & 31;
  const bool diag = (ib == jb);
  const int ibRow = ib * 128, jbRow = jb * 128;

  const int tid = threadIdx.x;
  const int lane = tid & 63;
  const int w = tid >> 6;
  const int fr = lane & 15;
  const int grp = lane >> 4;

  // ---- stage B panel: wave w converts+writes chunks {2w, 2w+1}, all slices
  {
    const int c0 = 2 * w, c1 = c0 + 1;
    const float* r0 = emb + (size_t)(jbRow + 16 * c0 + fr) * DD + grp * 8;
    const float* r1 = emb + (size_t)(jbRow + 16 * c1 + fr) * DD + grp * 8;
    #pragma unroll
    for (int s = 0; s < 8; ++s) {
      float4 v0 = *reinterpret_cast<const float4*>(r0 + 32 * s);
      float4 v1 = *reinterpret_cast<const float4*>(r0 + 32 * s + 4);
      *reinterpret_cast<ushort8v*>(&ldsB[s][c0 * 512 + lane * 8]) = pack8(v0, v1);
      float4 u0 = *reinterpret_cast<const float4*>(r1 + 32 * s);
      float4 u1 = *reinterpret_cast<const float4*>(r1 + 32 * s + 4);
      *reinterpret_cast<ushort8v*>(&ldsB[s][c1 * 512 + lane * 8]) = pack8(u0, u1);
    }
  }
  // ---- A panel into registers: rows 32w+16m+fr, cols grp*8 + 32s
  short8v a[8][2];
  #pragma unroll
  for (int m = 0; m < 2; ++m) {
    const float* ra = emb + (size_t)(ibRow + 32 * w + 16 * m + fr) * DD + grp * 8;
    #pragma unroll
    for (int s = 0; s < 8; ++s) {
      float4 v0 = *reinterpret_cast<const float4*>(ra + 32 * s);
      float4 v1 = *reinterpret_cast<const float4*>(ra + 32 * s + 4);
      ushort8v h = pack8(v0, v1);
      a[s][m] = *reinterpret_cast<short8v*>(&h);
    }
  }
  __syncthreads();  // one barrier: all B staged, A regs ready

  f32x4 acc[2][8];
  #pragma unroll
  for (int m = 0; m < 2; ++m)
    #pragma unroll
    for (int n = 0; n < 8; ++n)
      acc[m][n] = (f32x4){0.f, 0.f, 0.f, 0.f};

  #pragma unroll
  for (int s = 0; s < 8; ++s) {
    short8v b[8];
    #pragma unroll
    for (int n = 0; n < 8; ++n)
      b[n] = *reinterpret_cast<const short8v*>(&ldsB[s][n * 512 + lane * 8]);
    #pragma unroll
    for (int m = 0; m < 2; ++m)
      #pragma unroll
      for (int n = 0; n < 8; ++n)
        acc[m][n] = __builtin_amdgcn_mfma_f32_16x16x32_bf16(a[s][m], b[n], acc[m][n], 0, 0, 0);
  }

  // ---- epilogue on d^2 (sqrt monotone; ranking only — exact recompute later)
  // C layout: col = lane&15, row = (lane>>4)*4 + reg
  float sqjv[8]; int jglob[8];
  #pragma unroll
  for (int n = 0; n < 8; ++n) {
    jglob[n] = jbRow + n * 16 + fr;
    sqjv[n] = sq[jglob[n]];
  }

  #pragma unroll
  for (int m = 0; m < 2; ++m) {
    #pragma unroll
    for (int r = 0; r < 4; ++r) {
      const int gi = ibRow + w * 32 + m * 16 + grp * 4 + r;
      const float sqiv = sq[gi];
      float pv = -1.0f; int pj = -1;
      float nv = 3.0e38f; int nj = 0x7fffffff;
      #pragma unroll
      for (int n = 0; n < 8; ++n) {
        const float d2 = fmaxf(sqiv + sqjv[n] - 2.0f * acc[m][n][r], 0.0f);
        const int j = jglob[n];
        const bool isPos = diag && ((j >> 4) == (gi >> 4));
        if (isPos) {
          if (d2 > pv || (d2 == pv && j < pj)) { pv = d2; pj = j; }
        } else {
          if (d2 < nv || (d2 == nv && j < nj)) { nv = d2; nj = j; }
        }
      }
      #pragma unroll
      for (int off = 1; off < 16; off <<= 1) {
        float ov = __shfl_xor(nv, off); int oj = __shfl_xor(nj, off);
        if (ov < nv || (ov == nv && oj < nj)) { nv = ov; nj = oj; }
        float pov = __shfl_xor(pv, off); int poj = __shfl_xor(pj, off);
        if (pov > pv || (pov == pv && ((unsigned)poj < (unsigned)pj))) { pv = pov; pj = poj; }
      }
      if (fr == 0) {
        if (nj != 0x7fffffff)
          atomicMin(&negk[gi], ((u64)__float_as_uint(nv) << 32) | (unsigned)nj);
        if (diag && pj >= 0)
          atomicMax(&posk[gi], ((u64)__float_as_uint(pv) << 32) |
                                   (unsigned)(0xFFFFFFFFu - (unsigned)pj));
      }
    }
  }
}

// ---------------- kernel 2: exact fp32 triplet terms + fused mean -----------
// 256 blocks x 1024 threads = 16 waves = 16 rows/block; one atomicAdd/block.
__global__ __launch_bounds__(1024) void triplet_kernel(const float* __restrict__ emb,
                                                       const u64* __restrict__ posk,
                                                       const u64* __restrict__ negk,
                                                       float* __restrict__ out) {
  __shared__ float part[16];
  const int w = threadIdx.x >> 6;
  const int lane = threadIdx.x & 63;
  const int i = blockIdx.x * 16 + w;

  u64 pk = posk[i], nk = negk[i];
  int p = (int)(0xFFFFFFFFu - (unsigned)(pk & 0xFFFFFFFFu));
  int nidx = (int)(nk & 0xFFFFFFFFu);

  float4 e  = *reinterpret_cast<const float4*>(emb + (size_t)i * DD + 4 * lane);
  float4 ep = *reinterpret_cast<const float4*>(emb + (size_t)p * DD + 4 * lane);
  float4 en = *reinterpret_cast<const float4*>(emb + (size_t)nidx * DD + 4 * lane);

  float dpx = e.x - ep.x + EPSV, dpy = e.y - ep.y + EPSV,
        dpz = e.z - ep.z + EPSV, dpw = e.w - ep.w + EPSV;
  float dnx = e.x - en.x + EPSV, dny = e.y - en.y + EPSV,
        dnz = e.z - en.z + EPSV, dnw = e.w - en.w + EPSV;
  float sp = dpx * dpx + dpy * dpy + dpz * dpz + dpw * dpw;
  float sn = dnx * dnx + dny * dny + dnz * dnz + dnw * dnw;
  #pragma unroll
  for (int off = 32; off; off >>= 1) {
    sp += __shfl_xor(sp, off);
    sn += __shfl_xor(sn, off);
  }
  if (lane == 0) part[w] = fmaxf(sqrtf(sp) - sqrtf(sn) + 1.0f, 0.0f);
  __syncthreads();
  if (threadIdx.x == 0) {
    float s = 0.f;
    #pragma unroll
    for (int k = 0; k < 16; ++k) s += part[k];
    atomicAdd(out, s * (1.0f / NN));
  }
}

extern "C" void kernel_launch(void* const* d_in, const int* in_sizes, int n_in,
                              void* d_out, int out_size, void* d_ws, size_t ws_size,
                              hipStream_t stream) {
  const float* emb = (const float*)d_in[0];  // [N, D] row-major
  char* ws = (char*)d_ws;
  float* sq = (float*)ws;                  // 16 KB
  u64* posk = (u64*)(ws + (16 << 10));     // 32 KB
  u64* negk = (u64*)(ws + (48 << 10));     // 32 KB
  float* out = (float*)d_out;

  sqinit_kernel<<<256, 256, 0, stream>>>(emb, sq, posk, negk, out);
  mine_mfma_kernel<<<1024, 256, 0, stream>>>(emb, sq, posk, negk);
  triplet_kernel<<<256, 1024, 0, stream>>>(emb, posk, negk, out);
}

// Round 12
// 88.132 us; speedup vs baseline: 2.6271x; 1.2939x over previous
//
#include <hip/hip_runtime.h>
#include <math.h>

#define DD 256
#define NN 4096
#define EPSV 1e-6f

typedef unsigned long long u64;
typedef __attribute__((ext_vector_type(8))) short short8v;
typedef __attribute__((ext_vector_type(8))) unsigned short ushort8v;
typedef __attribute__((ext_vector_type(4))) float f32x4;

// ---------------- kernel 0: fused prep (verbatim from passing r6) ----------
// Block g handles rows 16g..16g+15: sq norms, key init, fp32 -> bf16(hi) in
// MFMA fragment order (A=B for Gram): lane l of frag (rowgroup g, kslice s)
// holds E[16g+(l&15)][32s+(l>>4)*8..+7], flat hi[((g*8+s)*64+l)*8+e].
__global__ __launch_bounds__(256) void prep_kernel(const float* __restrict__ emb,
                                                   float* __restrict__ sq,
                                                   unsigned short* __restrict__ hi,
                                                   u64* __restrict__ posk,
                                                   u64* __restrict__ negk,
                                                   float* __restrict__ out) {
  __shared__ __attribute__((aligned(16))) unsigned short hiS[16][264];
  const int g = blockIdx.x;  // 0..255
  const int t = threadIdx.x;
  const int r = t >> 4, q = t & 15;
  const int row = g * 16 + r;

  const float* src = emb + (size_t)row * DD + q * 16;
  float s = 0.f;
  #pragma unroll
  for (int i = 0; i < 4; ++i) {
    float4 v = *reinterpret_cast<const float4*>(src + 4 * i);
    float f[4] = {v.x, v.y, v.z, v.w};
    #pragma unroll
    for (int e = 0; e < 4; ++e) {
      s += f[e] * f[e];
      hiS[r][q * 16 + 4 * i + e] = (unsigned short)(__float_as_uint(f[e]) >> 16);
    }
  }
  #pragma unroll
  for (int off = 1; off < 16; off <<= 1) s += __shfl_xor(s, off);
  if (q == 0) {
    sq[row] = s;
    posk[row] = 0ull;   // max-key init
    negk[row] = ~0ull;  // min-key init
  }
  if (g == 0 && t == 0) out[0] = 0.0f;
  __syncthreads();

  #pragma unroll
  for (int h = 0; h < 2; ++h) {
    int q2 = h * 256 + t;  // 0..511
    int s2 = q2 >> 6, fl = q2 & 63;
    int col = 32 * s2 + 8 * (fl >> 4);
    ushort8v hv = *reinterpret_cast<const ushort8v*>(&hiS[fl & 15][col]);
    *reinterpret_cast<ushort8v*>(hi + ((size_t)(g * 8 + s2) * 64 + fl) * 8) = hv;
  }
}

// async 16B global->LDS copy (per-lane global addr, wave-uniform LDS base)
__device__ __forceinline__ void gll16(const unsigned short* g, unsigned short* l) {
  __builtin_amdgcn_global_load_lds(
      (const __attribute__((address_space(1))) unsigned int*)(const void*)g,
      (__attribute__((address_space(3))) unsigned int*)(void*)l, 16, 0, 0);
}

// ---------------- kernel 1: MFMA gram mining, 256x256 tile, ONE round ------
// 256 blocks (XCD-swizzled 16x16 grid) x 512 threads (8 waves), 1 block/CU.
// Wave w owns rows [32w, 32w+32) x all 256 cols (M_rep=2, N_rep=16).
// Whole B panel (128KB = 16 rowgroups x 8 slices) staged via 16 gll16/wave
// issued back-to-back; A panel (2 rowgroups/wave) in regs; ONE barrier; then
// 256 MFMAs/wave from LDS barrier-free. bf16-hi ranking; exact fp32 recompute
// in triplet_kernel.
__global__ __launch_bounds__(512, 2) void mine_mfma_kernel(const unsigned short* __restrict__ hi,
                                                           const float* __restrict__ sq,
                                                           u64* __restrict__ posk,
                                                           u64* __restrict__ negk) {
  __shared__ __attribute__((aligned(16))) unsigned short ldsB[8][8192];  // 128 KB

  // bijective XCD swizzle: 32 consecutive tiles per XCD (2 ib-stripes x 16 jb)
  const int bid = blockIdx.x;
  const int wg = (bid & 7) * 32 + (bid >> 3);
  const int ib = wg >> 4, jb = wg & 15;
  const bool diag = (ib == jb);
  const int ibRow = ib * 256, jbCol = jb * 256;

  const int tid = threadIdx.x;
  const int lane = tid & 63;
  const int w = tid >> 6;   // 0..7
  const int fr = lane & 15;
  const int grp = lane >> 4;

  // stage B panel: wave w stages chunks {2w, 2w+1} (of 16) for all 8 slices
  {
    const int c0 = 2 * w, c1 = c0 + 1;
    const unsigned short* g0 = hi + ((size_t)(jb * 16 + c0) * 8) * 512 + lane * 8;
    const unsigned short* g1 = hi + ((size_t)(jb * 16 + c1) * 8) * 512 + lane * 8;
    #pragma unroll
    for (int s = 0; s < 8; ++s) {
      gll16(g0 + s * 512, &ldsB[s][c0 * 512]);
      gll16(g1 + s * 512, &ldsB[s][c1 * 512]);
    }
  }
  // A panel into registers: wave w's rowgroups {ib*16+2w, +1}, all 8 slices
  short8v a[8][2];
  #pragma unroll
  for (int m = 0; m < 2; ++m) {
    const unsigned short* ga = hi + ((size_t)(ib * 16 + 2 * w + m) * 8) * 512 + lane * 8;
    #pragma unroll
    for (int s = 0; s < 8; ++s)
      a[s][m] = *reinterpret_cast<const short8v*>(ga + s * 512);
  }
  __syncthreads();  // ONE barrier: vmcnt drain of the 16KB/wave burst

  f32x4 acc[2][16];
  #pragma unroll
  for (int m = 0; m < 2; ++m)
    #pragma unroll
    for (int n = 0; n < 16; ++n)
      acc[m][n] = (f32x4){0.f, 0.f, 0.f, 0.f};

  #pragma unroll
  for (int s = 0; s < 8; ++s) {
    #pragma unroll
    for (int ng = 0; ng < 4; ++ng) {
      short8v b[4];
      #pragma unroll
      for (int k = 0; k < 4; ++k)
        b[k] = *reinterpret_cast<const short8v*>(&ldsB[s][(ng * 4 + k) * 512 + lane * 8]);
      #pragma unroll
      for (int m = 0; m < 2; ++m)
        #pragma unroll
        for (int k = 0; k < 4; ++k)
          acc[m][ng * 4 + k] =
              __builtin_amdgcn_mfma_f32_16x16x32_bf16(a[s][m], b[k], acc[m][ng * 4 + k], 0, 0, 0);
    }
  }

  // ---- epilogue on d^2 (sqrt monotone; ranking only — exact recompute later)
  // C layout: col = lane&15, row = (lane>>4)*4 + reg
  float sqjv[16]; int jglob[16];
  #pragma unroll
  for (int n = 0; n < 16; ++n) {
    jglob[n] = jbCol + n * 16 + fr;
    sqjv[n] = sq[jglob[n]];
  }

  #pragma unroll
  for (int m = 0; m < 2; ++m) {
    #pragma unroll
    for (int r = 0; r < 4; ++r) {
      const int gi = ibRow + 32 * w + 16 * m + 4 * grp + r;
      const float sqiv = sq[gi];
      float pv = -1.0f; int pj = -1;
      float nv = 3.0e38f; int nj = 0x7fffffff;
      #pragma unroll
      for (int n = 0; n < 16; ++n) {
        const float d2 = fmaxf(sqiv + sqjv[n] - 2.0f * acc[m][n][r], 0.0f);
        const int j = jglob[n];
        const bool isPos = diag && ((j >> 4) == (gi >> 4));
        if (isPos) {
          if (d2 > pv || (d2 == pv && j < pj)) { pv = d2; pj = j; }
        } else {
          if (d2 < nv || (d2 == nv && j < nj)) { nv = d2; nj = j; }
        }
      }
      #pragma unroll
      for (int off = 1; off < 16; off <<= 1) {
        float ov = __shfl_xor(nv, off); int oj = __shfl_xor(nj, off);
        if (ov < nv || (ov == nv && oj < nj)) { nv = ov; nj = oj; }
        float pov = __shfl_xor(pv, off); int poj = __shfl_xor(pj, off);
        if (pov > pv || (pov == pv && ((unsigned)poj < (unsigned)pj))) { pv = pov; pj = poj; }
      }
      if (fr == 0) {
        if (nj != 0x7fffffff)
          atomicMin(&negk[gi], ((u64)__float_as_uint(nv) << 32) | (unsigned)nj);
        if (diag && pj >= 0)
          atomicMax(&posk[gi], ((u64)__float_as_uint(pv) << 32) |
                                   (unsigned)(0xFFFFFFFFu - (unsigned)pj));
      }
    }
  }
}

// ---------------- kernel 2: exact fp32 triplet terms + fused mean -----------
// 256 blocks x 1024 threads = 16 waves = 16 rows/block; one atomicAdd/block.
__global__ __launch_bounds__(1024) void triplet_kernel(const float* __restrict__ emb,
                                                       const u64* __restrict__ posk,
                                                       const u64* __restrict__ negk,
                                                       float* __restrict__ out) {
  __shared__ float part[16];
  const int w = threadIdx.x >> 6;
  const int lane = threadIdx.x & 63;
  const int i = blockIdx.x * 16 + w;

  u64 pk = posk[i], nk = negk[i];
  int p = (int)(0xFFFFFFFFu - (unsigned)(pk & 0xFFFFFFFFu));
  int nidx = (int)(nk & 0xFFFFFFFFu);

  float4 e  = *reinterpret_cast<const float4*>(emb + (size_t)i * DD + 4 * lane);
  float4 ep = *reinterpret_cast<const float4*>(emb + (size_t)p * DD + 4 * lane);
  float4 en = *reinterpret_cast<const float4*>(emb + (size_t)nidx * DD + 4 * lane);

  float dpx = e.x - ep.x + EPSV, dpy = e.y - ep.y + EPSV,
        dpz = e.z - ep.z + EPSV, dpw = e.w - ep.w + EPSV;
  float dnx = e.x - en.x + EPSV, dny = e.y - en.y + EPSV,
        dnz = e.z - en.z + EPSV, dnw = e.w - en.w + EPSV;
  float sp = dpx * dpx + dpy * dpy + dpz * dpz + dpw * dpw;
  float sn = dnx * dnx + dny * dny + dnz * dnz + dnw * dnw;
  #pragma unroll
  for (int off = 32; off; off >>= 1) {
    sp += __shfl_xor(sp, off);
    sn += __shfl_xor(sn, off);
  }
  if (lane == 0) part[w] = fmaxf(sqrtf(sp) - sqrtf(sn) + 1.0f, 0.0f);
  __syncthreads();
  if (threadIdx.x == 0) {
    float s = 0.f;
    #pragma unroll
    for (int k = 0; k < 16; ++k) s += part[k];
    atomicAdd(out, s * (1.0f / NN));
  }
}

extern "C" void kernel_launch(void* const* d_in, const int* in_sizes, int n_in,
                              void* d_out, int out_size, void* d_ws, size_t ws_size,
                              hipStream_t stream) {
  const float* emb = (const float*)d_in[0];  // [N, D] row-major
  char* ws = (char*)d_ws;
  float* sq = (float*)ws;                  // 16 KB
  u64* posk = (u64*)(ws + (16 << 10));     // 32 KB
  u64* negk = (u64*)(ws + (48 << 10));     // 32 KB
  unsigned short* hi = (unsigned short*)(ws + (96 << 10));  // 2 MB
  float* out = (float*)d_out;

  prep_kernel<<<256, 256, 0, stream>>>(emb, sq, hi, posk, negk, out);
  mine_mfma_kernel<<<256, 512, 0, stream>>>(hi, sq, posk, negk);
  triplet_kernel<<<256, 1024, 0, stream>>>(emb, posk, negk, out);
}

// Round 13
// 85.557 us; speedup vs baseline: 2.7062x; 1.0301x over previous
//
#include <hip/hip_runtime.h>
#include <math.h>

#define DD 256
#define NN 4096
#define EPSV 1e-6f

typedef unsigned long long u64;
typedef __attribute__((ext_vector_type(8))) short short8v;
typedef __attribute__((ext_vector_type(8))) unsigned short ushort8v;
typedef __attribute__((ext_vector_type(4))) float f32x4;

// ---------------- kernel 0: fused prep ----------------
// Block g handles rows 16g..16g+15: sq norms, key init, fp32 -> bf16(hi) in
// MFMA fragment order (A=B for Gram): lane l of frag (rowgroup g, kslice s)
// holds E[16g+(l&15)][32s+(l>>4)*8..+7], flat hi[((g*8+s)*64+l)*8+e].
__global__ __launch_bounds__(256) void prep_kernel(const float* __restrict__ emb,
                                                   float* __restrict__ sq,
                                                   unsigned short* __restrict__ hi,
                                                   u64* __restrict__ posk,
                                                   u64* __restrict__ negk,
                                                   float* __restrict__ out) {
  __shared__ __attribute__((aligned(16))) unsigned short hiS[16][264];
  const int g = blockIdx.x;  // 0..255
  const int t = threadIdx.x;
  const int r = t >> 4, q = t & 15;
  const int row = g * 16 + r;

  const float* src = emb + (size_t)row * DD + q * 16;
  float s = 0.f;
  #pragma unroll
  for (int i = 0; i < 4; ++i) {
    float4 v = *reinterpret_cast<const float4*>(src + 4 * i);
    float f[4] = {v.x, v.y, v.z, v.w};
    #pragma unroll
    for (int e = 0; e < 4; ++e) {
      s += f[e] * f[e];
      hiS[r][q * 16 + 4 * i + e] = (unsigned short)(__float_as_uint(f[e]) >> 16);
    }
  }
  #pragma unroll
  for (int off = 1; off < 16; off <<= 1) s += __shfl_xor(s, off);
  if (q == 0) {
    sq[row] = s;
    posk[row] = 0ull;   // max-key init
    negk[row] = ~0ull;  // min-key init
  }
  if (g == 0 && t == 0) out[0] = 0.0f;
  __syncthreads();

  #pragma unroll
  for (int h = 0; h < 2; ++h) {
    int q2 = h * 256 + t;  // 0..511
    int s2 = q2 >> 6, fl = q2 & 63;
    int col = 32 * s2 + 8 * (fl >> 4);
    ushort8v hv = *reinterpret_cast<const ushort8v*>(&hiS[fl & 15][col]);
    *reinterpret_cast<ushort8v*>(hi + ((size_t)(g * 8 + s2) * 64 + fl) * 8) = hv;
  }
}

// async 16B global->LDS copy (per-lane global addr, wave-uniform LDS base)
__device__ __forceinline__ void gll16(const unsigned short* g, unsigned short* l) {
  __builtin_amdgcn_global_load_lds(
      (const __attribute__((address_space(1))) unsigned int*)(const void*)g,
      (__attribute__((address_space(3))) unsigned int*)(void*)l, 16, 0, 0);
}

// ---------------- kernel 1: MFMA gram mining, 256x256 tile, ONE round ------
// 256 blocks (XCD-swizzled 16x16 grid) x 512 threads (8 waves), 1 block/CU.
// Wave w owns rows [32w, 32w+32) x all 256 cols (M_rep=2, N_rep=16).
// B panel staged in TWO 64KB halves (slices 0-3, then 4-7): half2's staging
// issues before half1's MFMAs, so its latency hides under ~1.2us of compute.
// A panel (2 rowgroups/wave) in regs; sq gathers hoisted pre-barrier.
// bf16-hi ranking; exact fp32 recompute in triplet_kernel.
__global__ __launch_bounds__(512, 2) void mine_mfma_kernel(const unsigned short* __restrict__ hi,
                                                           const float* __restrict__ sq,
                                                           u64* __restrict__ posk,
                                                           u64* __restrict__ negk) {
  __shared__ __attribute__((aligned(16))) unsigned short ldsB[8][8192];  // 128 KB

  // bijective XCD swizzle: 32 consecutive tiles per XCD (2 ib-stripes x 16 jb)
  const int bid = blockIdx.x;
  const int wg = (bid & 7) * 32 + (bid >> 3);
  const int ib = wg >> 4, jb = wg & 15;
  const int ibRow = ib * 256, jbCol = jb * 256;

  const int tid = threadIdx.x;
  const int lane = tid & 63;
  const int w = tid >> 6;   // 0..7
  const int fr = lane & 15;
  const int grp = lane >> 4;

  const int c0 = 2 * w, c1 = c0 + 1;
  const unsigned short* g0 = hi + ((size_t)(jb * 16 + c0) * 8) * 512 + lane * 8;
  const unsigned short* g1 = hi + ((size_t)(jb * 16 + c1) * 8) * 512 + lane * 8;

  // stage half 1 (slices 0..3)
  #pragma unroll
  for (int s = 0; s < 4; ++s) {
    gll16(g0 + s * 512, &ldsB[s][c0 * 512]);
    gll16(g1 + s * 512, &ldsB[s][c1 * 512]);
  }
  // A panel into registers: wave w's rowgroups {ib*16+2w, +1}, all 8 slices
  short8v a[8][2];
  #pragma unroll
  for (int m = 0; m < 2; ++m) {
    const unsigned short* ga = hi + ((size_t)(ib * 16 + 2 * w + m) * 8) * 512 + lane * 8;
    #pragma unroll
    for (int s = 0; s < 8; ++s)
      a[s][m] = *reinterpret_cast<const short8v*>(ga + s * 512);
  }
  // hoist epilogue gathers off the critical path
  float sqjv[16]; int jglob[16];
  #pragma unroll
  for (int n = 0; n < 16; ++n) {
    jglob[n] = jbCol + n * 16 + fr;
    sqjv[n] = sq[jglob[n]];
  }
  float sqiv[2][4]; int iglob[2][4];
  #pragma unroll
  for (int m = 0; m < 2; ++m)
    #pragma unroll
    for (int r = 0; r < 4; ++r) {
      iglob[m][r] = ibRow + 32 * w + 16 * m + 4 * grp + r;
      sqiv[m][r] = sq[iglob[m][r]];
    }
  __syncthreads();  // barrier 1: half1 staged (+ A regs, sq gathers done)

  // issue half 2 staging (slices 4..7) BEFORE computing half 1
  #pragma unroll
  for (int s = 4; s < 8; ++s) {
    gll16(g0 + s * 512, &ldsB[s][c0 * 512]);
    gll16(g1 + s * 512, &ldsB[s][c1 * 512]);
  }

  f32x4 acc[2][16];
  #pragma unroll
  for (int m = 0; m < 2; ++m)
    #pragma unroll
    for (int n = 0; n < 16; ++n)
      acc[m][n] = (f32x4){0.f, 0.f, 0.f, 0.f};

  #pragma unroll
  for (int s = 0; s < 4; ++s) {
    #pragma unroll
    for (int ng = 0; ng < 4; ++ng) {
      short8v b[4];
      #pragma unroll
      for (int k = 0; k < 4; ++k)
        b[k] = *reinterpret_cast<const short8v*>(&ldsB[s][(ng * 4 + k) * 512 + lane * 8]);
      #pragma unroll
      for (int m = 0; m < 2; ++m)
        #pragma unroll
        for (int k = 0; k < 4; ++k)
          acc[m][ng * 4 + k] =
              __builtin_amdgcn_mfma_f32_16x16x32_bf16(a[s][m], b[k], acc[m][ng * 4 + k], 0, 0, 0);
    }
  }
  __syncthreads();  // barrier 2: half2 staged (latency hidden under half1 MFMA)
  #pragma unroll
  for (int s = 4; s < 8; ++s) {
    #pragma unroll
    for (int ng = 0; ng < 4; ++ng) {
      short8v b[4];
      #pragma unroll
      for (int k = 0; k < 4; ++k)
        b[k] = *reinterpret_cast<const short8v*>(&ldsB[s][(ng * 4 + k) * 512 + lane * 8]);
      #pragma unroll
      for (int m = 0; m < 2; ++m)
        #pragma unroll
        for (int k = 0; k < 4; ++k)
          acc[m][ng * 4 + k] =
              __builtin_amdgcn_mfma_f32_16x16x32_bf16(a[s][m], b[k], acc[m][ng * 4 + k], 0, 0, 0);
    }
  }

  // ---- epilogue on d^2 (sqrt monotone; ranking only — exact recompute later)
  // C layout: col = lane&15, row = (lane>>4)*4 + reg
  #pragma unroll
  for (int m = 0; m < 2; ++m) {
    #pragma unroll
    for (int r = 0; r < 4; ++r) {
      const int gi = iglob[m][r];
      const float sqr = sqiv[m][r];
      float pv = -1.0f; int pj = -1;
      float nv = 3.0e38f; int nj = 0x7fffffff;
      #pragma unroll
      for (int n = 0; n < 16; ++n) {
        const float d2 = fmaxf(sqr + sqjv[n] - 2.0f * acc[m][n][r], 0.0f);
        const int j = jglob[n];
        const bool isPos = ((j >> 4) == (gi >> 4));
        if (isPos) {
          if (d2 > pv || (d2 == pv && j < pj)) { pv = d2; pj = j; }
        } else {
          if (d2 < nv || (d2 == nv && j < nj)) { nv = d2; nj = j; }
        }
      }
      #pragma unroll
      for (int off = 1; off < 16; off <<= 1) {
        float ov = __shfl_xor(nv, off); int oj = __shfl_xor(nj, off);
        if (ov < nv || (ov == nv && oj < nj)) { nv = ov; nj = oj; }
        float pov = __shfl_xor(pv, off); int poj = __shfl_xor(pj, off);
        if (pov > pv || (pov == pv && ((unsigned)poj < (unsigned)pj))) { pv = pov; pj = poj; }
      }
      if (fr == 0) {
        if (nj != 0x7fffffff)
          atomicMin(&negk[gi], ((u64)__float_as_uint(nv) << 32) | (unsigned)nj);
        if (pj >= 0)
          atomicMax(&posk[gi], ((u64)__float_as_uint(pv) << 32) |
                                   (unsigned)(0xFFFFFFFFu - (unsigned)pj));
      }
    }
  }
}

// ---------------- kernel 2: exact fp32 triplet terms + fused mean -----------
// 256 blocks x 1024 threads = 16 waves = 16 rows/block; one atomicAdd/block.
__global__ __launch_bounds__(1024) void triplet_kernel(const float* __restrict__ emb,
                                                       const u64* __restrict__ posk,
                                                       const u64* __restrict__ negk,
                                                       float* __restrict__ out) {
  __shared__ float part[16];
  const int w = threadIdx.x >> 6;
  const int lane = threadIdx.x & 63;
  const int i = blockIdx.x * 16 + w;

  u64 pk = posk[i], nk = negk[i];
  int p = (int)(0xFFFFFFFFu - (unsigned)(pk & 0xFFFFFFFFu));
  int nidx = (int)(nk & 0xFFFFFFFFu);

  float4 e  = *reinterpret_cast<const float4*>(emb + (size_t)i * DD + 4 * lane);
  float4 ep = *reinterpret_cast<const float4*>(emb + (size_t)p * DD + 4 * lane);
  float4 en = *reinterpret_cast<const float4*>(emb + (size_t)nidx * DD + 4 * lane);

  float dpx = e.x - ep.x + EPSV, dpy = e.y - ep.y + EPSV,
        dpz = e.z - ep.z + EPSV, dpw = e.w - ep.w + EPSV;
  float dnx = e.x - en.x + EPSV, dny = e.y - en.y + EPSV,
        dnz = e.z - en.z + EPSV, dnw = e.w - en.w + EPSV;
  float sp = dpx * dpx + dpy * dpy + dpz * dpz + dpw * dpw;
  float sn = dnx * dnx + dny * dny + dnz * dnz + dnw * dnw;
  #pragma unroll
  for (int off = 32; off; off >>= 1) {
    sp += __shfl_xor(sp, off);
    sn += __shfl_xor(sn, off);
  }
  if (lane == 0) part[w] = fmaxf(sqrtf(sp) - sqrtf(sn) + 1.0f, 0.0f);
  __syncthreads();
  if (threadIdx.x == 0) {
    float s = 0.f;
    #pragma unroll
    for (int k = 0; k < 16; ++k) s += part[k];
    atomicAdd(out, s * (1.0f / NN));
  }
}

extern "C" void kernel_launch(void* const* d_in, const int* in_sizes, int n_in,
                              void* d_out, int out_size, void* d_ws, size_t ws_size,
                              hipStream_t stream) {
  const float* emb = (const float*)d_in[0];  // [N, D] row-major
  char* ws = (char*)d_ws;
  float* sq = (float*)ws;                  // 16 KB
  u64* posk = (u64*)(ws + (16 << 10));     // 32 KB
  u64* negk = (u64*)(ws + (48 << 10));     // 32 KB
  unsigned short* hi = (unsigned short*)(ws + (96 << 10));  // 2 MB
  float* out = (float*)d_out;

  prep_kernel<<<256, 256, 0, stream>>>(emb, sq, hi, posk, negk, out);
  mine_mfma_kernel<<<256, 512, 0, stream>>>(hi, sq, posk, negk);
  triplet_kernel<<<256, 1024, 0, stream>>>(emb, posk, negk, out);
}

// Round 14
// 85.393 us; speedup vs baseline: 2.7114x; 1.0019x over previous
//
#include <hip/hip_runtime.h>
#include <math.h>

#define DD 256
#define NN 4096
#define EPSV 1e-6f

typedef unsigned long long u64;
typedef __attribute__((ext_vector_type(8))) short short8v;
typedef __attribute__((ext_vector_type(8))) unsigned short ushort8v;
typedef __attribute__((ext_vector_type(4))) float f32x4;

// ---------------- kernel 0: fused prep ----------------
// Block g handles rows 16g..16g+15: sq norms, key init, fp32 -> bf16(hi) in
// MFMA fragment order (A=B for Gram): lane l of frag (rowgroup g, kslice s)
// holds E[16g+(l&15)][32s+(l>>4)*8..+7], flat hi[((g*8+s)*64+l)*8+e].
__global__ __launch_bounds__(256) void prep_kernel(const float* __restrict__ emb,
                                                   float* __restrict__ sq,
                                                   unsigned short* __restrict__ hi,
                                                   u64* __restrict__ posk,
                                                   u64* __restrict__ negk,
                                                   float* __restrict__ out) {
  __shared__ __attribute__((aligned(16))) unsigned short hiS[16][264];
  const int g = blockIdx.x;  // 0..255
  const int t = threadIdx.x;
  const int r = t >> 4, q = t & 15;
  const int row = g * 16 + r;

  const float* src = emb + (size_t)row * DD + q * 16;
  float s = 0.f;
  #pragma unroll
  for (int i = 0; i < 4; ++i) {
    float4 v = *reinterpret_cast<const float4*>(src + 4 * i);
    float f[4] = {v.x, v.y, v.z, v.w};
    #pragma unroll
    for (int e = 0; e < 4; ++e) {
      s += f[e] * f[e];
      hiS[r][q * 16 + 4 * i + e] = (unsigned short)(__float_as_uint(f[e]) >> 16);
    }
  }
  #pragma unroll
  for (int off = 1; off < 16; off <<= 1) s += __shfl_xor(s, off);
  if (q == 0) {
    sq[row] = s;
    posk[row] = 0ull;   // max-key init
    negk[row] = ~0ull;  // min-key init
  }
  if (g == 0 && t == 0) out[0] = 0.0f;
  __syncthreads();

  #pragma unroll
  for (int h = 0; h < 2; ++h) {
    int q2 = h * 256 + t;  // 0..511
    int s2 = q2 >> 6, fl = q2 & 63;
    int col = 32 * s2 + 8 * (fl >> 4);
    ushort8v hv = *reinterpret_cast<const ushort8v*>(&hiS[fl & 15][col]);
    *reinterpret_cast<ushort8v*>(hi + ((size_t)(g * 8 + s2) * 64 + fl) * 8) = hv;
  }
}

// async 16B global->LDS copy (per-lane global addr, wave-uniform LDS base)
__device__ __forceinline__ void gll16(const unsigned short* g, unsigned short* l) {
  __builtin_amdgcn_global_load_lds(
      (const __attribute__((address_space(1))) unsigned int*)(const void*)g,
      (__attribute__((address_space(3))) unsigned int*)(void*)l, 16, 0, 0);
}

// ---------------- kernel 1: MFMA gram mining, 256x256 tile, ONE round ------
// 256 blocks (XCD-swizzled 16x16 grid) x 512 threads (8 waves), 1 block/CU.
// Wave w owns rows [32w, 32w+32) x all 256 cols (M_rep=2, N_rep=16).
// B panel staged in FOUR 32KB quarters (2 slices each): quarter q+1's staging
// issues right after the barrier that publishes quarter q, and its ~512cy of
// data transfer hides under quarter q's ~640cy of MFMA. Only the initial
// 32KB stage is latency-exposed. A panel (2 rowgroups/wave) in regs; sq
// gathers hoisted pre-barrier. bf16-hi ranking; exact fp32 recompute follows.
__global__ __launch_bounds__(512, 2) void mine_mfma_kernel(const unsigned short* __restrict__ hi,
                                                           const float* __restrict__ sq,
                                                           u64* __restrict__ posk,
                                                           u64* __restrict__ negk) {
  __shared__ __attribute__((aligned(16))) unsigned short ldsB[8][8192];  // 128 KB

  // bijective XCD swizzle: 32 consecutive tiles per XCD (2 ib-stripes x 16 jb)
  const int bid = blockIdx.x;
  const int wg = (bid & 7) * 32 + (bid >> 3);
  const int ib = wg >> 4, jb = wg & 15;
  const int ibRow = ib * 256, jbCol = jb * 256;

  const int tid = threadIdx.x;
  const int lane = tid & 63;
  const int w = tid >> 6;   // 0..7
  const int fr = lane & 15;
  const int grp = lane >> 4;

  const int c0 = 2 * w, c1 = c0 + 1;
  const unsigned short* g0 = hi + ((size_t)(jb * 16 + c0) * 8) * 512 + lane * 8;
  const unsigned short* g1 = hi + ((size_t)(jb * 16 + c1) * 8) * 512 + lane * 8;

  // stage quarter 0 (slices 0,1)
  #pragma unroll
  for (int s = 0; s < 2; ++s) {
    gll16(g0 + s * 512, &ldsB[s][c0 * 512]);
    gll16(g1 + s * 512, &ldsB[s][c1 * 512]);
  }
  // A panel into registers: wave w's rowgroups {ib*16+2w, +1}, all 8 slices
  short8v a[8][2];
  #pragma unroll
  for (int m = 0; m < 2; ++m) {
    const unsigned short* ga = hi + ((size_t)(ib * 16 + 2 * w + m) * 8) * 512 + lane * 8;
    #pragma unroll
    for (int s = 0; s < 8; ++s)
      a[s][m] = *reinterpret_cast<const short8v*>(ga + s * 512);
  }
  // hoist epilogue gathers off the critical path
  float sqjv[16]; int jglob[16];
  #pragma unroll
  for (int n = 0; n < 16; ++n) {
    jglob[n] = jbCol + n * 16 + fr;
    sqjv[n] = sq[jglob[n]];
  }
  float sqiv[2][4]; int iglob[2][4];
  #pragma unroll
  for (int m = 0; m < 2; ++m)
    #pragma unroll
    for (int r = 0; r < 4; ++r) {
      iglob[m][r] = ibRow + 32 * w + 16 * m + 4 * grp + r;
      sqiv[m][r] = sq[iglob[m][r]];
    }

  f32x4 acc[2][16];
  #pragma unroll
  for (int m = 0; m < 2; ++m)
    #pragma unroll
    for (int n = 0; n < 16; ++n)
      acc[m][n] = (f32x4){0.f, 0.f, 0.f, 0.f};

  // 4-quarter pipeline: bar(q ready) -> issue q+1 -> compute q
  #pragma unroll
  for (int qt = 0; qt < 4; ++qt) {
    __syncthreads();  // quarter qt staged (vmcnt drain covered by qt-1 MFMA)
    if (qt < 3) {     // issue quarter qt+1 (slices 2qt+2, 2qt+3)
      #pragma unroll
      for (int s = 2 * qt + 2; s < 2 * qt + 4; ++s) {
        gll16(g0 + s * 512, &ldsB[s][c0 * 512]);
        gll16(g1 + s * 512, &ldsB[s][c1 * 512]);
      }
    }
    #pragma unroll
    for (int s = 2 * qt; s < 2 * qt + 2; ++s) {
      #pragma unroll
      for (int ng = 0; ng < 4; ++ng) {
        short8v b[4];
        #pragma unroll
        for (int k = 0; k < 4; ++k)
          b[k] = *reinterpret_cast<const short8v*>(&ldsB[s][(ng * 4 + k) * 512 + lane * 8]);
        #pragma unroll
        for (int m = 0; m < 2; ++m)
          #pragma unroll
          for (int k = 0; k < 4; ++k)
            acc[m][ng * 4 + k] =
                __builtin_amdgcn_mfma_f32_16x16x32_bf16(a[s][m], b[k], acc[m][ng * 4 + k], 0, 0, 0);
      }
    }
  }

  // ---- epilogue on d^2 (sqrt monotone; ranking only — exact recompute later)
  // C layout: col = lane&15, row = (lane>>4)*4 + reg
  #pragma unroll
  for (int m = 0; m < 2; ++m) {
    #pragma unroll
    for (int r = 0; r < 4; ++r) {
      const int gi = iglob[m][r];
      const float sqr = sqiv[m][r];
      float pv = -1.0f; int pj = -1;
      float nv = 3.0e38f; int nj = 0x7fffffff;
      #pragma unroll
      for (int n = 0; n < 16; ++n) {
        const float d2 = fmaxf(sqr + sqjv[n] - 2.0f * acc[m][n][r], 0.0f);
        const int j = jglob[n];
        const bool isPos = ((j >> 4) == (gi >> 4));
        if (isPos) {
          if (d2 > pv || (d2 == pv && j < pj)) { pv = d2; pj = j; }
        } else {
          if (d2 < nv || (d2 == nv && j < nj)) { nv = d2; nj = j; }
        }
      }
      #pragma unroll
      for (int off = 1; off < 16; off <<= 1) {
        float ov = __shfl_xor(nv, off); int oj = __shfl_xor(nj, off);
        if (ov < nv || (ov == nv && oj < nj)) { nv = ov; nj = oj; }
        float pov = __shfl_xor(pv, off); int poj = __shfl_xor(pj, off);
        if (pov > pv || (pov == pv && ((unsigned)poj < (unsigned)pj))) { pv = pov; pj = poj; }
      }
      if (fr == 0) {
        if (nj != 0x7fffffff)
          atomicMin(&negk[gi], ((u64)__float_as_uint(nv) << 32) | (unsigned)nj);
        if (pj >= 0)
          atomicMax(&posk[gi], ((u64)__float_as_uint(pv) << 32) |
                                   (unsigned)(0xFFFFFFFFu - (unsigned)pj));
      }
    }
  }
}

// ---------------- kernel 2: exact fp32 triplet terms + fused mean -----------
// 256 blocks x 1024 threads = 16 waves = 16 rows/block; one atomicAdd/block.
__global__ __launch_bounds__(1024) void triplet_kernel(const float* __restrict__ emb,
                                                       const u64* __restrict__ posk,
                                                       const u64* __restrict__ negk,
                                                       float* __restrict__ out) {
  __shared__ float part[16];
  const int w = threadIdx.x >> 6;
  const int lane = threadIdx.x & 63;
  const int i = blockIdx.x * 16 + w;

  u64 pk = posk[i], nk = negk[i];
  int p = (int)(0xFFFFFFFFu - (unsigned)(pk & 0xFFFFFFFFu));
  int nidx = (int)(nk & 0xFFFFFFFFu);

  float4 e  = *reinterpret_cast<const float4*>(emb + (size_t)i * DD + 4 * lane);
  float4 ep = *reinterpret_cast<const float4*>(emb + (size_t)p * DD + 4 * lane);
  float4 en = *reinterpret_cast<const float4*>(emb + (size_t)nidx * DD + 4 * lane);

  float dpx = e.x - ep.x + EPSV, dpy = e.y - ep.y + EPSV,
        dpz = e.z - ep.z + EPSV, dpw = e.w - ep.w + EPSV;
  float dnx = e.x - en.x + EPSV, dny = e.y - en.y + EPSV,
        dnz = e.z - en.z + EPSV, dnw = e.w - en.w + EPSV;
  float sp = dpx * dpx + dpy * dpy + dpz * dpz + dpw * dpw;
  float sn = dnx * dnx + dny * dny + dnz * dnz + dnw * dnw;
  #pragma unroll
  for (int off = 32; off; off >>= 1) {
    sp += __shfl_xor(sp, off);
    sn += __shfl_xor(sn, off);
  }
  if (lane == 0) part[w] = fmaxf(sqrtf(sp) - sqrtf(sn) + 1.0f, 0.0f);
  __syncthreads();
  if (threadIdx.x == 0) {
    float s = 0.f;
    #pragma unroll
    for (int k = 0; k < 16; ++k) s += part[k];
    atomicAdd(out, s * (1.0f / NN));
  }
}

extern "C" void kernel_launch(void* const* d_in, const int* in_sizes, int n_in,
                              void* d_out, int out_size, void* d_ws, size_t ws_size,
                              hipStream_t stream) {
  const float* emb = (const float*)d_in[0];  // [N, D] row-major
  char* ws = (char*)d_ws;
  float* sq = (float*)ws;                  // 16 KB
  u64* posk = (u64*)(ws + (16 << 10));     // 32 KB
  u64* negk = (u64*)(ws + (48 << 10));     // 32 KB
  unsigned short* hi = (unsigned short*)(ws + (96 << 10));  // 2 MB
  float* out = (float*)d_out;

  prep_kernel<<<256, 256, 0, stream>>>(emb, sq, hi, posk, negk, out);
  mine_mfma_kernel<<<256, 512, 0, stream>>>(hi, sq, posk, negk);
  triplet_kernel<<<256, 1024, 0, stream>>>(emb, posk, negk, out);
}